// Round 11
// baseline (153.169 us; speedup 1.0000x reference)
//
#include <hip/hip_runtime.h>

typedef __bf16 bf16_t;
typedef bf16_t bf16x8 __attribute__((ext_vector_type(8)));
typedef unsigned short ushort8_t __attribute__((ext_vector_type(8)));
typedef unsigned short ushort4_t __attribute__((ext_vector_type(4)));
typedef float f32x4 __attribute__((ext_vector_type(4)));

__device__ __forceinline__ unsigned short f2bf(float f) {
    __bf16 h = (__bf16)f;
    return __builtin_bit_cast(unsigned short, h);
}
__device__ __forceinline__ float fast_tanh(float x) {
    float e2 = __expf(2.f * x);
    return 1.f - 2.f / (e2 + 1.f);
}
__device__ __forceinline__ float fast_sig(float x) {
    return 1.f / (1.f + __expf(-x));
}

// ---------------- K0: two 512x512 transpose+bf16 converts in one launch ----------------
__global__ void k0_wt2(const float* __restrict__ Wi2h, const float* __restrict__ Wh2h,
                       unsigned short* __restrict__ Wt, unsigned short* __restrict__ Wht) {
    __shared__ float tile[32][33];
    const float* W = blockIdx.z ? Wh2h : Wi2h;
    unsigned short* O = blockIdx.z ? Wht : Wt;
    int tx = threadIdx.x, ty = threadIdx.y;
    int bx = blockIdx.x, by = blockIdx.y;
#pragma unroll
    for (int j = 0; j < 4; ++j) {
        int r = by * 32 + ty + j * 8;
        int c = bx * 32 + tx;
        tile[ty + j * 8][tx] = W[r * 512 + c];
    }
    __syncthreads();
#pragma unroll
    for (int j = 0; j < 4; ++j) {
        int h = bx * 32 + ty + j * 8;
        int d = by * 32 + tx;
        O[h * 512 + d] = f2bf(tile[tx][ty + j * 8]);
    }
}

// ---------------- K1x: bf16 convert (float4 -> ushort4) ----------------
__global__ void k1x_conv(const float* __restrict__ src, unsigned short* __restrict__ dst) {
    int i = blockIdx.x * 256 + threadIdx.x;
    float4 f = ((const float4*)src)[i];
    ushort4_t u;
    u[0] = f2bf(f.x); u[1] = f2bf(f.y); u[2] = f2bf(f.z); u[3] = f2bf(f.w);
    ((ushort4_t*)dst)[i] = u;
}

// ---------------- K1m: h_proj = prev_h @ Wh2h + bh2h via MFMA ----------------
__global__ void k1m_hproj(const unsigned short* __restrict__ ph_bf,
                          const unsigned short* __restrict__ Wht,
                          const float* __restrict__ bh2h,
                          float* __restrict__ h_proj) {
    int tid = threadIdx.x;
    int wave = tid >> 6, lane = tid & 63;
    int l15 = lane & 15, g = lane >> 4;
    int h0 = blockIdx.x * 64 + wave * 16;
    int m0 = blockIdx.y * 32;

    f32x4 acc[2];
    acc[0] = (f32x4){0.f, 0.f, 0.f, 0.f};
    acc[1] = (f32x4){0.f, 0.f, 0.f, 0.f};

    const unsigned short* abase = ph_bf + (size_t)(m0 + l15) * 512 + g * 8;
    const unsigned short* bbase = Wht + (size_t)(h0 + l15) * 512 + g * 8;
#pragma unroll
    for (int j = 0; j < 16; ++j) {
        bf16x8 bf = __builtin_bit_cast(bf16x8, *(const ushort8_t*)(bbase + j * 32));
        bf16x8 a0 = __builtin_bit_cast(bf16x8, *(const ushort8_t*)(abase + j * 32));
        bf16x8 a1 = __builtin_bit_cast(bf16x8, *(const ushort8_t*)(abase + 16 * 512 + j * 32));
        acc[0] = __builtin_amdgcn_mfma_f32_16x16x32_bf16(a0, bf, acc[0], 0, 0, 0);
        acc[1] = __builtin_amdgcn_mfma_f32_16x16x32_bf16(a1, bf, acc[1], 0, 0, 0);
    }
    int h = h0 + l15;
    float bias = bh2h[h];
#pragma unroll
    for (int mf = 0; mf < 2; ++mf)
#pragma unroll
        for (int r = 0; r < 4; ++r)
            h_proj[(size_t)(m0 + mf * 16 + g * 4 + r) * 512 + h] = acc[mf][r] + bias;
}

// ---------------- K2 v7: ring-3 depth-2 pipelined fused e-GEMM ----------------
// Grid 2048 = 512 mt x 4 nt (XCD-swizzled), 256 threads = 4 waves (2wr x 2wc).
// Block tile 128x128, K=512, BK=32 -> 16 K-tiles, LDS ring of 3 slots (A 8KB + B 8KB each).
// Per tile t: ds_write A(t+1) (held regs) | issue B(t+2) gload_lds + A(t+2) reg loads |
// compute tile t | lgkmcnt(0) + RAW s_barrier (no vmcnt drain -> loads fly across barriers).
// B(k) completion enforced by FIFO vmcnt: A(k) regs issued after B(k) (sched_barrier pin),
// consumed one iteration before B(k)'s LDS reads. Swizzle: chunk ^= (row>>1)&3 (2-way free).
__launch_bounds__(256, 2)
__global__ void k2_scores(const float* __restrict__ batch_H,
                          const unsigned short* __restrict__ Wt,
                          const float* __restrict__ h_proj,
                          const float* __restrict__ Wscore,
                          float* __restrict__ e_part) {
    __shared__ __align__(16) char Asl[3][8192];
    __shared__ __align__(16) char Bsl[3][8192];
    __shared__ float hp_s[128];
    __shared__ float wsc_s[128];
    __shared__ float e_red[4][64];

    int tid = threadIdx.x;
    int wg = (blockIdx.x & 7) * 256 + (blockIdx.x >> 3);
    int mt = wg >> 2, nt = wg & 3;
    int m0 = mt * 128, n0 = nt * 128;
    int b  = m0 >> 8;

    if (tid < 128) hp_s[tid] = h_proj[(size_t)b * 512 + n0 + tid];
    else           wsc_s[tid - 128] = Wscore[n0 + tid - 128];

    int wave = tid >> 6;
    int lane = tid & 63;
    int wr = wave >> 1, wc = wave & 1;
    int l15 = lane & 15, g = lane >> 4;
    int brow0 = lane >> 2;        // 0..15 row within 16-row gload group
    int bs    = lane & 3;         // LDS chunk slot this lane fills
    int ar8 = tid >> 3;           // 0..31 A-stage row within 32-row pass
    int ac4 = tid & 7;            // A-stage float4 col

    f32x4 acc[4][4];
#pragma unroll
    for (int mf = 0; mf < 4; ++mf)
#pragma unroll
        for (int nf = 0; nf < 4; ++nf)
            acc[mf][nf] = (f32x4){0.f, 0.f, 0.f, 0.f};

    float4 av0[4], av1[4];

#define STAGE_B(tile, slot)                                                              \
    {                                                                                    \
        _Pragma("unroll")                                                                \
        for (int i_ = 0; i_ < 2; ++i_) {                                                 \
            int rowbase_ = (wave * 2 + i_) * 16;                                         \
            int row_ = rowbase_ + brow0;                                                 \
            int chunk_ = bs ^ ((row_ >> 1) & 3);                                         \
            const unsigned short* src_ = Wt + (size_t)(n0 + row_) * 512 + (tile) * 32 + chunk_ * 8; \
            __builtin_amdgcn_global_load_lds(                                            \
                (const __attribute__((address_space(1))) void*)src_,                     \
                (__attribute__((address_space(3))) void*)(&Bsl[slot][rowbase_ * 64]), 16, 0, 0); \
        }                                                                                \
    }

#define LOAD_A(avreg, tile)                                                              \
    {                                                                                    \
        _Pragma("unroll")                                                                \
        for (int p_ = 0; p_ < 4; ++p_)                                                   \
            avreg[p_] = *(const float4*)(batch_H + (size_t)(m0 + p_ * 32 + ar8) * 512 + (tile) * 32 + ac4 * 4); \
    }

#define WRITE_A(avreg, slot)                                                             \
    {                                                                                    \
        _Pragma("unroll")                                                                \
        for (int p_ = 0; p_ < 4; ++p_) {                                                 \
            int r_ = p_ * 32 + ar8;                                                      \
            ushort4_t u_;                                                                \
            u_[0] = f2bf(avreg[p_].x); u_[1] = f2bf(avreg[p_].y);                        \
            u_[2] = f2bf(avreg[p_].z); u_[3] = f2bf(avreg[p_].w);                        \
            int off_ = r_ * 64 + ((((ac4 >> 1) ^ ((r_ >> 1) & 3))) << 4) + ((ac4 & 1) << 3); \
            *(ushort4_t*)(&Asl[slot][off_]) = u_;                                        \
        }                                                                                \
    }

    // ---- prologue: B(0)->slot0, B(1)->slot1, then A(0),A(1) regs, write A(0) ----
    STAGE_B(0, 0)
    STAGE_B(1, 1)
    __builtin_amdgcn_sched_barrier(0);
    LOAD_A(av0, 0)
    LOAD_A(av1, 1)
    WRITE_A(av0, 0)     // consuming av0 FIFO-drains B(0),B(1); av1 stays in flight
    asm volatile("s_waitcnt lgkmcnt(0)" ::: "memory");
    __builtin_amdgcn_s_barrier();
    __builtin_amdgcn_sched_barrier(0);

#pragma unroll
    for (int t = 0; t < 16; ++t) {
        const int slotC = t % 3, slotW = (t + 1) % 3, slotL = (t + 2) % 3;
        // (1) write A(t+1) from held regs (auto-drains B(t+1) via FIFO vmcnt)
        if (t < 15) {
            if (t & 1) { WRITE_A(av0, slotW) }   // tile t+1 even -> av0
            else       { WRITE_A(av1, slotW) }   // tile t+1 odd  -> av1
        }
        // (2) issue next-next tile's loads: B first, then A (order pinned)
        if (t < 14) {
            STAGE_B(t + 2, slotL)
            __builtin_amdgcn_sched_barrier(0);
            if (t & 1) { LOAD_A(av1, t + 2) }
            else       { LOAD_A(av0, t + 2) }
        }
        // (3) compute tile t from slotC
        {
            bf16x8 af[4], bfr[4];
#pragma unroll
            for (int mf = 0; mf < 4; ++mf) {
                int row = wr * 64 + mf * 16 + l15;
                af[mf] = __builtin_bit_cast(bf16x8,
                    *(const ushort8_t*)(&Asl[slotC][row * 64 + (((g ^ ((row >> 1) & 3))) << 4)]));
            }
#pragma unroll
            for (int nf = 0; nf < 4; ++nf) {
                int row = wc * 64 + nf * 16 + l15;
                bfr[nf] = __builtin_bit_cast(bf16x8,
                    *(const ushort8_t*)(&Bsl[slotC][row * 64 + (((g ^ ((row >> 1) & 3))) << 4)]));
            }
            __builtin_amdgcn_s_setprio(1);
#pragma unroll
            for (int nf = 0; nf < 4; ++nf)
#pragma unroll
                for (int mf = 0; mf < 4; ++mf)
                    acc[mf][nf] = __builtin_amdgcn_mfma_f32_16x16x32_bf16(
                        af[mf], bfr[nf], acc[mf][nf], 0, 0, 0);
            __builtin_amdgcn_s_setprio(0);
        }
        // (4) LDS fence + raw barrier: vmcnt NOT drained (B/A loads stay in flight)
        asm volatile("s_waitcnt lgkmcnt(0)" ::: "memory");
        __builtin_amdgcn_sched_barrier(0);
        __builtin_amdgcn_s_barrier();
        __builtin_amdgcn_sched_barrier(0);
    }
#undef STAGE_B
#undef LOAD_A
#undef WRITE_A

    // ---- epilogue: partial e over this block's 128 n-cols (r4-identical) ----
    float s[4][4];
#pragma unroll
    for (int mf = 0; mf < 4; ++mf)
#pragma unroll
        for (int r = 0; r < 4; ++r) s[mf][r] = 0.f;

#pragma unroll
    for (int nf = 0; nf < 4; ++nf) {
        int nl = wc * 64 + nf * 16 + l15;
        float hpv = hp_s[nl], wv = wsc_s[nl];
#pragma unroll
        for (int mf = 0; mf < 4; ++mf)
#pragma unroll
            for (int r = 0; r < 4; ++r)
                s[mf][r] += wv * fast_tanh(acc[mf][nf][r] + hpv);
    }
#pragma unroll
    for (int mf = 0; mf < 4; ++mf)
#pragma unroll
        for (int r = 0; r < 4; ++r) {
            float v = s[mf][r];
            v += __shfl_xor(v, 1);
            v += __shfl_xor(v, 2);
            v += __shfl_xor(v, 4);
            v += __shfl_xor(v, 8);
            s[mf][r] = v;
        }
    if (l15 == 0) {
#pragma unroll
        for (int mf = 0; mf < 4; ++mf)
#pragma unroll
            for (int r = 0; r < 4; ++r)
                e_red[wave][mf * 16 + g * 4 + r] = s[mf][r];
    }
    __syncthreads();
    if (tid < 128) {
        int wrr = tid >> 6, i64 = tid & 63;
        float v = e_red[wrr * 2 + 0][i64] + e_red[wrr * 2 + 1][i64];
        e_part[(size_t)nt * 65536 + m0 + tid] = v;
    }
}

// ---------------- K3: sum 4 e-partials + softmax over T per b ----------------
__global__ void k3_softmax(const float* __restrict__ e_part, float* __restrict__ alpha_out) {
    __shared__ float red[4];
    int b = blockIdx.x, tid = threadIdx.x;
    int m = b * 256 + tid;
    float v = e_part[m] + e_part[65536 + m] + e_part[131072 + m] + e_part[196608 + m];
    float mx = v;
#pragma unroll
    for (int off = 32; off; off >>= 1) mx = fmaxf(mx, __shfl_xor(mx, off));
    if ((tid & 63) == 0) red[tid >> 6] = mx;
    __syncthreads();
    mx = fmaxf(fmaxf(red[0], red[1]), fmaxf(red[2], red[3]));
    float p = __expf(v - mx);
    __syncthreads();
    float sum = p;
#pragma unroll
    for (int off = 32; off; off >>= 1) sum += __shfl_xor(sum, off);
    if ((tid & 63) == 0) red[tid >> 6] = sum;
    __syncthreads();
    sum = red[0] + red[1] + red[2] + red[3];
    alpha_out[b * 256 + tid] = p / sum;
}

// ---------------- K4: context[b,d] = sum_t alpha[b,t] * batch_H[b,t,d] ----------------
__global__ void k4_context(const float* __restrict__ batch_H, const float* __restrict__ alpha,
                           float* __restrict__ context) {
    __shared__ float al[256];
    int b = blockIdx.y, dc = blockIdx.x, tid = threadIdx.x;
    al[tid] = alpha[b * 256 + tid];
    __syncthreads();
    int d = dc * 256 + tid;
    const float* bh = batch_H + (size_t)b * 256 * 512 + d;
    float acc = 0.f;
#pragma unroll 4
    for (int t = 0; t < 256; ++t)
        acc += al[t] * bh[(size_t)t * 512];
    context[b * 512 + d] = acc;
}

// ---------------- K5t: Wzt[n][k] = bf16([Wk;Uk][k][n]) ----------------
__global__ void k5t_wzt(const float* __restrict__ Wk, const float* __restrict__ Uk,
                        unsigned short* __restrict__ Wzt) {
    __shared__ float tile[32][33];
    int tx = threadIdx.x, ty = threadIdx.y;
    int bx = blockIdx.x;
    int by = blockIdx.y;
#pragma unroll
    for (int j = 0; j < 4; ++j) {
        int k = bx * 32 + ty + j * 8;
        int c = by * 32 + tx;
        float v = (k < 608) ? Wk[(size_t)k * 2048 + c] : Uk[(size_t)(k - 608) * 2048 + c];
        tile[ty + j * 8][tx] = v;
    }
    __syncthreads();
#pragma unroll
    for (int j = 0; j < 4; ++j) {
        int n = by * 32 + ty + j * 8;
        int k = bx * 32 + tx;
        Wzt[(size_t)n * 1120 + k] = f2bf(tile[tx][ty + j * 8]);
    }
}

// ---------------- K5x: xb[b][k] = bf16([context;onehots;prev_h]) ----------------
__global__ void k5x_build(const float* __restrict__ context, const float* __restrict__ onehots,
                          const float* __restrict__ prev_h, unsigned short* __restrict__ xb) {
    int b = blockIdx.x, tid = threadIdx.x;
    for (int k = tid; k < 1120; k += 256) {
        float v;
        if (k < 512)      v = context[b * 512 + k];
        else if (k < 608) v = onehots[b * 96 + k - 512];
        else              v = prev_h[b * 512 + k - 608];
        xb[(size_t)b * 1120 + k] = f2bf(v);
    }
}

// ---------------- K5m: fused z-GEMM + LSTM gates ----------------
__launch_bounds__(256)
__global__ void k5m_fused(const unsigned short* __restrict__ xb,
                          const unsigned short* __restrict__ Wzt,
                          const float* __restrict__ bk,
                          const float* __restrict__ prev_c,
                          float* __restrict__ out) {
    __shared__ __align__(16) unsigned short Axs[32 * 232];

    int tid  = threadIdx.x;
    int wave = tid >> 6;
    int lane = tid & 63;
    int l15  = lane & 15;
    int g    = lane >> 4;
    int b0   = blockIdx.y * 32;
    int h0   = blockIdx.x * 64 + wave * 16;

    f32x4 acc[2][4];
#pragma unroll
    for (int mf = 0; mf < 2; ++mf)
#pragma unroll
        for (int gt = 0; gt < 4; ++gt)
            acc[mf][gt] = (f32x4){0.f, 0.f, 0.f, 0.f};

    const unsigned short* wbase = Wzt + (size_t)(h0 + l15) * 1120;

    for (int ks = 0; ks < 5; ++ks) {
        if (ks) __syncthreads();
        int kbase = ks * 224;
        for (int i = tid; i < 896; i += 256) {
            int row = i / 28;
            int c8  = (i % 28) * 8;
            *(ushort8_t*)(&Axs[row * 232 + c8]) =
                *(const ushort8_t*)(&xb[(size_t)(b0 + row) * 1120 + kbase + c8]);
        }
        __syncthreads();

        bf16x8 bcur[4], bnxt[4];
#pragma unroll
        for (int gt = 0; gt < 4; ++gt)
            bcur[gt] = __builtin_bit_cast(bf16x8,
                *(const ushort8_t*)(wbase + (size_t)gt * 512 * 1120 + kbase + g * 8));

#pragma unroll
        for (int kb = 0; kb < 7; ++kb) {
            if (kb < 6) {
                int kg = kbase + (kb + 1) * 32 + g * 8;
#pragma unroll
                for (int gt = 0; gt < 4; ++gt)
                    bnxt[gt] = __builtin_bit_cast(bf16x8,
                        *(const ushort8_t*)(wbase + (size_t)gt * 512 * 1120 + kg));
            }
            bf16x8 afrag[2];
#pragma unroll
            for (int mf = 0; mf < 2; ++mf)
                afrag[mf] = __builtin_bit_cast(bf16x8,
                    *(const ushort8_t*)(&Axs[(mf * 16 + l15) * 232 + kb * 32 + g * 8]));
#pragma unroll
            for (int gt = 0; gt < 4; ++gt)
#pragma unroll
                for (int mf = 0; mf < 2; ++mf)
                    acc[mf][gt] = __builtin_amdgcn_mfma_f32_16x16x32_bf16(
                        afrag[mf], bcur[gt], acc[mf][gt], 0, 0, 0);
#pragma unroll
            for (int gt = 0; gt < 4; ++gt) bcur[gt] = bnxt[gt];
        }
    }

    int h = h0 + l15;
    float bi = bk[h], bfv = bk[512 + h], bg = bk[1024 + h], bo = bk[1536 + h];
#pragma unroll
    for (int mf = 0; mf < 2; ++mf)
#pragma unroll
        for (int r = 0; r < 4; ++r) {
            int m = b0 + mf * 16 + g * 4 + r;
            float zi = acc[mf][0][r] + bi;
            float zf = acc[mf][1][r] + bfv;
            float zg = acc[mf][2][r] + bg;
            float zo = acc[mf][3][r] + bo;
            float c  = fast_sig(zf) * prev_c[m * 512 + h] + fast_sig(zi) * fast_tanh(zg);
            float hn = fast_sig(zo) * fast_tanh(c);
            out[m * 512 + h]          = hn;
            out[131072 + m * 512 + h] = c;
        }
}

extern "C" void kernel_launch(void* const* d_in, const int* in_sizes, int n_in,
                              void* d_out, int out_size, void* d_ws, size_t ws_size,
                              hipStream_t stream) {
    (void)in_sizes; (void)n_in; (void)out_size; (void)ws_size;
    const float* prev_h  = (const float*)d_in[0];
    const float* prev_c  = (const float*)d_in[1];
    const float* batch_H = (const float*)d_in[2];
    const float* onehots = (const float*)d_in[3];
    const float* Wi2h    = (const float*)d_in[4];
    const float* Wh2h    = (const float*)d_in[5];
    const float* bh2h    = (const float*)d_in[6];
    const float* Wscore  = (const float*)d_in[7];
    const float* Wk      = (const float*)d_in[8];
    const float* Uk      = (const float*)d_in[9];
    const float* bk      = (const float*)d_in[10];
    float* out = (float*)d_out;
    float* alpha = out + 262144;

    char* ws = (char*)d_ws;
    // Phase A (dead by k5t): [0, 2883584)
    unsigned short* Wt     = (unsigned short*)(ws + 0);        // 524288
    unsigned short* Wht    = (unsigned short*)(ws + 524288);   // 524288
    unsigned short* ph_bf  = (unsigned short*)(ws + 1048576);  // 262144
    float*          h_proj = (float*)(ws + 1310720);           // 524288
    float*          e_part = (float*)(ws + 1835008);           // 1048576, ends 2883584
    // Phase B: Wzt overwrites [0, 4587520) after Phase A dead
    unsigned short* Wzt    = (unsigned short*)(ws + 0);        // 4587520
    unsigned short* xb     = (unsigned short*)(ws + 4587520);  // 573440, ends 5160960
    float*          context= (float*)(ws + 5160960);           // 524288, ends 5685248

    k0_wt2    <<<dim3(16, 16, 2), dim3(32, 8), 0, stream>>>(Wi2h, Wh2h, Wt, Wht);
    k1x_conv  <<<128, 256, 0, stream>>>(prev_h, ph_bf);
    k1m_hproj <<<dim3(8, 8), 256, 0, stream>>>(ph_bf, Wht, bh2h, h_proj);
    k2_scores <<<2048, 256, 0, stream>>>(batch_H, Wt, h_proj, Wscore, e_part);
    k3_softmax<<<256, 256, 0, stream>>>(e_part, alpha);
    k4_context<<<dim3(2, 256), 256, 0, stream>>>(batch_H, alpha, context);
    k5t_wzt   <<<dim3(35, 64), dim3(32, 8), 0, stream>>>(Wk, Uk, Wzt);
    k5x_build <<<256, 256, 0, stream>>>(context, onehots, prev_h, xb);
    k5m_fused <<<dim3(8, 8), 256, 0, stream>>>(xb, Wzt, bk, prev_c, out);
}

// Round 12
// 147.196 us; speedup vs baseline: 1.0406x; 1.0406x over previous
//
#include <hip/hip_runtime.h>

typedef __bf16 bf16_t;
typedef bf16_t bf16x8 __attribute__((ext_vector_type(8)));
typedef unsigned short ushort8_t __attribute__((ext_vector_type(8)));
typedef unsigned short ushort4_t __attribute__((ext_vector_type(4)));
typedef float f32x4 __attribute__((ext_vector_type(4)));

__device__ __forceinline__ unsigned short f2bf(float f) {
    __bf16 h = (__bf16)f;
    return __builtin_bit_cast(unsigned short, h);
}
__device__ __forceinline__ float fast_tanh(float x) {
    float e2 = __expf(2.f * x);
    return 1.f - 2.f / (e2 + 1.f);
}
__device__ __forceinline__ float fast_sig(float x) {
    return 1.f / (1.f + __expf(-x));
}
__device__ __forceinline__ ushort8_t cvt8(float4 f0, float4 f1) {
    ushort8_t u;
    u[0] = f2bf(f0.x); u[1] = f2bf(f0.y); u[2] = f2bf(f0.z); u[3] = f2bf(f0.w);
    u[4] = f2bf(f1.x); u[5] = f2bf(f1.y); u[6] = f2bf(f1.z); u[7] = f2bf(f1.w);
    return u;
}

// ---------------- K0: two 512x512 transpose+bf16 converts in one launch ----------------
__global__ void k0_wt2(const float* __restrict__ Wi2h, const float* __restrict__ Wh2h,
                       unsigned short* __restrict__ Wt, unsigned short* __restrict__ Wht) {
    __shared__ float tile[32][33];
    const float* W = blockIdx.z ? Wh2h : Wi2h;
    unsigned short* O = blockIdx.z ? Wht : Wt;
    int tx = threadIdx.x, ty = threadIdx.y;
    int bx = blockIdx.x, by = blockIdx.y;
#pragma unroll
    for (int j = 0; j < 4; ++j) {
        int r = by * 32 + ty + j * 8;
        int c = bx * 32 + tx;
        tile[ty + j * 8][tx] = W[r * 512 + c];
    }
    __syncthreads();
#pragma unroll
    for (int j = 0; j < 4; ++j) {
        int h = bx * 32 + ty + j * 8;
        int d = by * 32 + tx;
        O[h * 512 + d] = f2bf(tile[tx][ty + j * 8]);
    }
}

// ---------------- K1m: h_proj = prev_h @ Wh2h + bh2h via MFMA (inline fp32->bf16 A) ----------------
__global__ void k1m_hproj(const float* __restrict__ prev_h,
                          const unsigned short* __restrict__ Wht,
                          const float* __restrict__ bh2h,
                          float* __restrict__ h_proj) {
    int tid = threadIdx.x;
    int wave = tid >> 6, lane = tid & 63;
    int l15 = lane & 15, g = lane >> 4;
    int h0 = blockIdx.x * 64 + wave * 16;
    int m0 = blockIdx.y * 32;

    f32x4 acc[2];
    acc[0] = (f32x4){0.f, 0.f, 0.f, 0.f};
    acc[1] = (f32x4){0.f, 0.f, 0.f, 0.f};

    const float* abase = prev_h + (size_t)(m0 + l15) * 512 + g * 8;
    const unsigned short* bbase = Wht + (size_t)(h0 + l15) * 512 + g * 8;
#pragma unroll
    for (int j = 0; j < 16; ++j) {
        bf16x8 bf = __builtin_bit_cast(bf16x8, *(const ushort8_t*)(bbase + j * 32));
        float4 f0 = *(const float4*)(abase + j * 32);
        float4 f1 = *(const float4*)(abase + j * 32 + 4);
        bf16x8 a0 = __builtin_bit_cast(bf16x8, cvt8(f0, f1));
        float4 f2 = *(const float4*)(abase + 16 * 512 + j * 32);
        float4 f3 = *(const float4*)(abase + 16 * 512 + j * 32 + 4);
        bf16x8 a1 = __builtin_bit_cast(bf16x8, cvt8(f2, f3));
        acc[0] = __builtin_amdgcn_mfma_f32_16x16x32_bf16(a0, bf, acc[0], 0, 0, 0);
        acc[1] = __builtin_amdgcn_mfma_f32_16x16x32_bf16(a1, bf, acc[1], 0, 0, 0);
    }
    int h = h0 + l15;
    float bias = bh2h[h];
#pragma unroll
    for (int mf = 0; mf < 2; ++mf)
#pragma unroll
        for (int r = 0; r < 4; ++r)
            h_proj[(size_t)(m0 + mf * 16 + g * 4 + r) * 512 + h] = acc[mf][r] + bias;
}

// ---------------- K2 (r4-proven m97 structure; lb(256,3): residency up, VGPR uncapped) ----------------
__launch_bounds__(256, 3)
__global__ void k2_scores(const float* __restrict__ batch_H,
                          const unsigned short* __restrict__ Wt,
                          const float* __restrict__ h_proj,
                          const float* __restrict__ Wscore,
                          float* __restrict__ e_part) {
    __shared__ __align__(16) unsigned short Alds[8192];
    __shared__ __align__(16) unsigned short Blds[8192];
    __shared__ float hp_s[128];
    __shared__ float wsc_s[128];
    __shared__ float e_red[4][64];

    int tid = threadIdx.x;
    int wg = (blockIdx.x & 7) * 256 + (blockIdx.x >> 3);
    int mt = wg >> 2, nt = wg & 3;
    int m0 = mt * 128, n0 = nt * 128;
    int b  = m0 >> 8;

    if (tid < 128) hp_s[tid] = h_proj[(size_t)b * 512 + n0 + tid];
    else           wsc_s[tid - 128] = Wscore[n0 + tid - 128];

    int wave = tid >> 6;
    int lane = tid & 63;
    int wr = wave >> 1;
    int wc = wave & 1;
    int l15 = lane & 15, g = lane >> 4;
    int bchunk = ((lane & 7) ^ (lane >> 3)) << 3;
    int brow_l = lane >> 3;

    f32x4 acc[4][4];
#pragma unroll
    for (int mf = 0; mf < 4; ++mf)
#pragma unroll
        for (int nf = 0; nf < 4; ++nf)
            acc[mf][nf] = (f32x4){0.f, 0.f, 0.f, 0.f};

    for (int ks = 0; ks < 8; ++ks) {
        __syncthreads();
        int kbase = ks * 64;
#pragma unroll
        for (int i = 0; i < 4; ++i) {
            int q = wave * 4 + i;
            int row = q * 8 + brow_l;
            const unsigned short* gsrc = Wt + (size_t)(n0 + row) * 512 + kbase + bchunk;
            __builtin_amdgcn_global_load_lds(
                (const __attribute__((address_space(1))) void*)gsrc,
                (__attribute__((address_space(3))) void*)&Blds[q * 512], 16, 0, 0);
        }
        float4 av[8];
#pragma unroll
        for (int j = 0; j < 8; ++j) {
            int idx = j * 256 + tid;
            int r = idx >> 4, c4 = idx & 15;
            av[j] = *(const float4*)(batch_H + (size_t)(m0 + r) * 512 + kbase + c4 * 4);
        }
#pragma unroll
        for (int j = 0; j < 8; ++j) {
            int idx = j * 256 + tid;
            int r = idx >> 4, c4 = idx & 15;
            ushort4_t u;
            u[0] = f2bf(av[j].x); u[1] = f2bf(av[j].y);
            u[2] = f2bf(av[j].z); u[3] = f2bf(av[j].w);
            int boff = r * 128 + ((((c4 >> 1) ^ (r & 7)) << 4) | ((c4 & 1) << 3));
            *(ushort4_t*)((char*)Alds + boff) = u;
        }
        __syncthreads();
#pragma unroll
        for (int kk = 0; kk < 2; ++kk) {
            bf16x8 af[4], bfr[4];
#pragma unroll
            for (int mf = 0; mf < 4; ++mf) {
                int row = wr * 64 + mf * 16 + l15;
                int boff = row * 128 + ((((kk * 4 + g) ^ (l15 & 7))) << 4);
                af[mf] = __builtin_bit_cast(bf16x8, *(const ushort8_t*)((char*)Alds + boff));
            }
#pragma unroll
            for (int nf = 0; nf < 4; ++nf) {
                int row = wc * 64 + nf * 16 + l15;
                int boff = row * 128 + ((((kk * 4 + g) ^ (l15 & 7))) << 4);
                bfr[nf] = __builtin_bit_cast(bf16x8, *(const ushort8_t*)((char*)Blds + boff));
            }
#pragma unroll
            for (int nf = 0; nf < 4; ++nf)
#pragma unroll
                for (int mf = 0; mf < 4; ++mf)
                    acc[mf][nf] = __builtin_amdgcn_mfma_f32_16x16x32_bf16(
                        af[mf], bfr[nf], acc[mf][nf], 0, 0, 0);
        }
    }

    float s[4][4];
#pragma unroll
    for (int mf = 0; mf < 4; ++mf)
#pragma unroll
        for (int r = 0; r < 4; ++r) s[mf][r] = 0.f;

#pragma unroll
    for (int nf = 0; nf < 4; ++nf) {
        int nl = wc * 64 + nf * 16 + l15;
        float hpv = hp_s[nl], wv = wsc_s[nl];
#pragma unroll
        for (int mf = 0; mf < 4; ++mf)
#pragma unroll
            for (int r = 0; r < 4; ++r)
                s[mf][r] += wv * fast_tanh(acc[mf][nf][r] + hpv);
    }
#pragma unroll
    for (int mf = 0; mf < 4; ++mf)
#pragma unroll
        for (int r = 0; r < 4; ++r) {
            float v = s[mf][r];
            v += __shfl_xor(v, 1);
            v += __shfl_xor(v, 2);
            v += __shfl_xor(v, 4);
            v += __shfl_xor(v, 8);
            s[mf][r] = v;
        }
    if (l15 == 0) {
#pragma unroll
        for (int mf = 0; mf < 4; ++mf)
#pragma unroll
            for (int r = 0; r < 4; ++r)
                e_red[wave][mf * 16 + g * 4 + r] = s[mf][r];
    }
    __syncthreads();
    if (tid < 128) {
        int wrr = tid >> 6, i64 = tid & 63;
        float v = e_red[wrr * 2 + 0][i64] + e_red[wrr * 2 + 1][i64];
        e_part[(size_t)nt * 65536 + m0 + tid] = v;
    }
}

// ---------------- K3K4: softmax (4-partial sum) + context, fused ----------------
__global__ void k3k4_fused(const float* __restrict__ e_part, const float* __restrict__ batch_H,
                           float* __restrict__ alpha_out, float* __restrict__ context) {
    __shared__ float red[4];
    __shared__ float al[256];
    int b = blockIdx.x, tid = threadIdx.x;
    int m = b * 256 + tid;
    float v = e_part[m] + e_part[65536 + m] + e_part[131072 + m] + e_part[196608 + m];
    float mx = v;
#pragma unroll
    for (int off = 32; off; off >>= 1) mx = fmaxf(mx, __shfl_xor(mx, off));
    if ((tid & 63) == 0) red[tid >> 6] = mx;
    __syncthreads();
    mx = fmaxf(fmaxf(red[0], red[1]), fmaxf(red[2], red[3]));
    float p = __expf(v - mx);
    __syncthreads();
    float sum = p;
#pragma unroll
    for (int off = 32; off; off >>= 1) sum += __shfl_xor(sum, off);
    if ((tid & 63) == 0) red[tid >> 6] = sum;
    __syncthreads();
    sum = red[0] + red[1] + red[2] + red[3];
    float a = p / sum;
    alpha_out[b * 256 + tid] = a;
    al[tid] = a;
    __syncthreads();
    // context: two d-columns per thread
    const float* bh = batch_H + (size_t)b * 131072;
    float ac0 = 0.f, ac1 = 0.f;
#pragma unroll 4
    for (int t = 0; t < 256; ++t) {
        float av = al[t];
        ac0 += av * bh[t * 512 + tid];
        ac1 += av * bh[t * 512 + tid + 256];
    }
    context[b * 512 + tid]       = ac0;
    context[b * 512 + tid + 256] = ac1;
}

// ---------------- K5t: Wzt[n][k] = bf16([Wk;Uk][k][n]) ----------------
__global__ void k5t_wzt(const float* __restrict__ Wk, const float* __restrict__ Uk,
                        unsigned short* __restrict__ Wzt) {
    __shared__ float tile[32][33];
    int tx = threadIdx.x, ty = threadIdx.y;
    int bx = blockIdx.x;
    int by = blockIdx.y;
#pragma unroll
    for (int j = 0; j < 4; ++j) {
        int k = bx * 32 + ty + j * 8;
        int c = by * 32 + tx;
        float v = (k < 608) ? Wk[(size_t)k * 2048 + c] : Uk[(size_t)(k - 608) * 2048 + c];
        tile[ty + j * 8][tx] = v;
    }
    __syncthreads();
#pragma unroll
    for (int j = 0; j < 4; ++j) {
        int n = by * 32 + ty + j * 8;
        int k = bx * 32 + tx;
        Wzt[(size_t)n * 1120 + k] = f2bf(tile[tx][ty + j * 8]);
    }
}

// ---------------- K5m: fused x-build + z-GEMM + LSTM gates ----------------
// Staging reads context/onehots/prev_h fp32 directly (8-chunks never straddle 512/608).
__launch_bounds__(256)
__global__ void k5m_fused(const float* __restrict__ context, const float* __restrict__ onehots,
                          const float* __restrict__ prev_h,
                          const unsigned short* __restrict__ Wzt,
                          const float* __restrict__ bk,
                          const float* __restrict__ prev_c,
                          float* __restrict__ out) {
    __shared__ __align__(16) unsigned short Axs[32 * 232];

    int tid  = threadIdx.x;
    int wave = tid >> 6;
    int lane = tid & 63;
    int l15  = lane & 15;
    int g    = lane >> 4;
    int b0   = blockIdx.y * 32;
    int h0   = blockIdx.x * 64 + wave * 16;

    f32x4 acc[2][4];
#pragma unroll
    for (int mf = 0; mf < 2; ++mf)
#pragma unroll
        for (int gt = 0; gt < 4; ++gt)
            acc[mf][gt] = (f32x4){0.f, 0.f, 0.f, 0.f};

    const unsigned short* wbase = Wzt + (size_t)(h0 + l15) * 1120;

    for (int ks = 0; ks < 5; ++ks) {
        if (ks) __syncthreads();
        int kbase = ks * 224;
        for (int i = tid; i < 896; i += 256) {
            int row = i / 28;
            int c8  = (i % 28) * 8;
            int gk  = kbase + c8;
            int gb  = b0 + row;
            ushort8_t u;
            if (gk < 512) {
                const float* s = context + (size_t)gb * 512 + gk;
                u = cvt8(*(const float4*)s, *(const float4*)(s + 4));
            } else if (gk < 608) {
                const float* s = onehots + (size_t)gb * 96 + (gk - 512);
                u = cvt8(*(const float4*)s, *(const float4*)(s + 4));
            } else {
                const float* s = prev_h + (size_t)gb * 512 + (gk - 608);
                u = cvt8(*(const float4*)s, *(const float4*)(s + 4));
            }
            *(ushort8_t*)(&Axs[row * 232 + c8]) = u;
        }
        __syncthreads();

        bf16x8 bcur[4], bnxt[4];
#pragma unroll
        for (int gt = 0; gt < 4; ++gt)
            bcur[gt] = __builtin_bit_cast(bf16x8,
                *(const ushort8_t*)(wbase + (size_t)gt * 512 * 1120 + kbase + g * 8));

#pragma unroll
        for (int kb = 0; kb < 7; ++kb) {
            if (kb < 6) {
                int kg = kbase + (kb + 1) * 32 + g * 8;
#pragma unroll
                for (int gt = 0; gt < 4; ++gt)
                    bnxt[gt] = __builtin_bit_cast(bf16x8,
                        *(const ushort8_t*)(wbase + (size_t)gt * 512 * 1120 + kg));
            }
            bf16x8 afrag[2];
#pragma unroll
            for (int mf = 0; mf < 2; ++mf)
                afrag[mf] = __builtin_bit_cast(bf16x8,
                    *(const ushort8_t*)(&Axs[(mf * 16 + l15) * 232 + kb * 32 + g * 8]));
#pragma unroll
            for (int gt = 0; gt < 4; ++gt)
#pragma unroll
                for (int mf = 0; mf < 2; ++mf)
                    acc[mf][gt] = __builtin_amdgcn_mfma_f32_16x16x32_bf16(
                        afrag[mf], bcur[gt], acc[mf][gt], 0, 0, 0);
#pragma unroll
            for (int gt = 0; gt < 4; ++gt) bcur[gt] = bnxt[gt];
        }
    }

    int h = h0 + l15;
    float bi = bk[h], bfv = bk[512 + h], bg = bk[1024 + h], bo = bk[1536 + h];
#pragma unroll
    for (int mf = 0; mf < 2; ++mf)
#pragma unroll
        for (int r = 0; r < 4; ++r) {
            int m = b0 + mf * 16 + g * 4 + r;
            float zi = acc[mf][0][r] + bi;
            float zf = acc[mf][1][r] + bfv;
            float zg = acc[mf][2][r] + bg;
            float zo = acc[mf][3][r] + bo;
            float c  = fast_sig(zf) * prev_c[m * 512 + h] + fast_sig(zi) * fast_tanh(zg);
            float hn = fast_sig(zo) * fast_tanh(c);
            out[m * 512 + h]          = hn;
            out[131072 + m * 512 + h] = c;
        }
}

extern "C" void kernel_launch(void* const* d_in, const int* in_sizes, int n_in,
                              void* d_out, int out_size, void* d_ws, size_t ws_size,
                              hipStream_t stream) {
    (void)in_sizes; (void)n_in; (void)out_size; (void)ws_size;
    const float* prev_h  = (const float*)d_in[0];
    const float* prev_c  = (const float*)d_in[1];
    const float* batch_H = (const float*)d_in[2];
    const float* onehots = (const float*)d_in[3];
    const float* Wi2h    = (const float*)d_in[4];
    const float* Wh2h    = (const float*)d_in[5];
    const float* bh2h    = (const float*)d_in[6];
    const float* Wscore  = (const float*)d_in[7];
    const float* Wk      = (const float*)d_in[8];
    const float* Uk      = (const float*)d_in[9];
    const float* bk      = (const float*)d_in[10];
    float* out = (float*)d_out;
    float* alpha = out + 262144;

    char* ws = (char*)d_ws;
    // Phase A (all dead before k5t): [0, 2621440)
    unsigned short* Wt     = (unsigned short*)(ws + 0);        // 524288
    unsigned short* Wht    = (unsigned short*)(ws + 524288);   // 524288
    float*          h_proj = (float*)(ws + 1048576);           // 524288
    float*          e_part = (float*)(ws + 1572864);           // 1048576, ends 2621440
    // Phase B: Wzt overwrites [0, 4587520) after Phase A dead; context beyond.
    unsigned short* Wzt    = (unsigned short*)(ws + 0);        // 4587520
    float*          context= (float*)(ws + 4587520);           // 524288, ends 5111808

    k0_wt2    <<<dim3(16, 16, 2), dim3(32, 8), 0, stream>>>(Wi2h, Wh2h, Wt, Wht);
    k1m_hproj <<<dim3(8, 8), 256, 0, stream>>>(prev_h, Wht, bh2h, h_proj);
    k2_scores <<<2048, 256, 0, stream>>>(batch_H, Wt, h_proj, Wscore, e_part);
    k3k4_fused<<<256, 256, 0, stream>>>(e_part, batch_H, alpha, context);
    k5t_wzt   <<<dim3(35, 64), dim3(32, 8), 0, stream>>>(Wk, Uk, Wzt);
    k5m_fused <<<dim3(8, 8), 256, 0, stream>>>(context, onehots, prev_h, Wzt, bk, prev_c, out);
}